// Round 11
// baseline (668.288 us; speedup 1.0000x reference)
//
#include <hip/hip_runtime.h>

#define NN 100000
#define NE 1600000
#define HD 128
#define EPSI 1e-5f

using u32 = unsigned int;
using u16 = unsigned short;

typedef short bf16x8 __attribute__((ext_vector_type(8)));
typedef float f32x4  __attribute__((ext_vector_type(4)));
typedef u32   u32x4  __attribute__((ext_vector_type(4)));

constexpr int SCAN_CHUNK  = 1024;
constexpr int SCAN_BLOCKS = (NN + SCAN_CHUNK - 1) / SCAN_CHUNK; // 98
constexpr int NRANGE      = 128;                  // dst ranges (one fill/count block each)
constexpr int RSZ2        = 784;                  // nodes per range (128*784 >= NN), < 1024 for packing
constexpr int BINCAP      = 16384;                // u32 slots per bin (mean 12544)
constexpr int PART_CHUNK4 = 1024;                 // int4s per block in k_part (4096 edges)
constexpr int PART_GRID   = (NE / 4 + PART_CHUNK4 - 1) / PART_CHUNK4; // 391

// Activations are CHUNK-TILED: buf[chunk][node][8 bf16], chunk = col/8 (16 chunks).
// k_agg pins chunk-slices to XCDs via blockIdx%16 so each XCD's gather working
// set is 2 chunks = 3.2 MB < 4 MB L2.

// ---- bf16 helpers (storage bf16, arithmetic fp32) ----
__device__ inline float bflo(u32 u) { return __uint_as_float(u << 16); }
__device__ inline float bfhi(u32 u) { return __uint_as_float(u & 0xFFFF0000u); }
__device__ inline u16 f2bf(float f) {
    u32 u = __float_as_uint(f);
    u += 0x7FFFu + ((u >> 16) & 1u); // RNE
    return (u16)(u >> 16);
}
__device__ inline u32 pack2(float a, float b) {
    return (u32)f2bf(a) | ((u32)f2bf(b) << 16);
}

// ---------------- CSR build: single-read 128-bin partition (u32-packed), LDS-ranked fill ----------------

__global__ __launch_bounds__(256) void k_part(const int* __restrict__ src,
                                              const int* __restrict__ dst,
                                              int* __restrict__ binCur,
                                              u32* __restrict__ binbuf) {
    __shared__ int hist[NRANGE], base[NRANGE], curs[NRANGE];
    const int t  = threadIdx.x;
    const int c0 = blockIdx.x * PART_CHUNK4;
    if (t < NRANGE) { hist[t] = 0; curs[t] = 0; }
    __syncthreads();

    int4 ds[4], ss[4];
    bool ok[4];
#pragma unroll
    for (int i = 0; i < 4; ++i) {
        const int c = c0 + t + 256 * i;
        ok[i] = c < NE / 4;
        if (ok[i]) {
            ds[i] = reinterpret_cast<const int4*>(dst)[c];
            ss[i] = reinterpret_cast<const int4*>(src)[c];
        }
    }
#pragma unroll
    for (int i = 0; i < 4; ++i) {
        if (ok[i]) {
            atomicAdd(&hist[ds[i].x / RSZ2], 1);
            atomicAdd(&hist[ds[i].y / RSZ2], 1);
            atomicAdd(&hist[ds[i].z / RSZ2], 1);
            atomicAdd(&hist[ds[i].w / RSZ2], 1);
        }
    }
    __syncthreads();
    if (t < NRANGE && hist[t] > 0) base[t] = atomicAdd(&binCur[t], hist[t]);
    __syncthreads();

#pragma unroll
    for (int i = 0; i < 4; ++i) {
        if (ok[i]) {
            const int d[4] = {ds[i].x, ds[i].y, ds[i].z, ds[i].w};
            const int s[4] = {ss[i].x, ss[i].y, ss[i].z, ss[i].w};
#pragma unroll
            for (int j = 0; j < 4; ++j) {
                const int r  = d[j] / RSZ2;
                const int ld = d[j] - r * RSZ2;      // < 1024
                const int p  = base[r] + atomicAdd(&curs[r], 1);
                if (p < BINCAP)
                    binbuf[(size_t)r * BINCAP + p] = ((u32)s[j] << 10) | (u32)ld;
            }
        }
    }
}

// one block per range: per-node counts via LDS histogram, non-atomic cnt write
__global__ __launch_bounds__(1024) void k_countL(const int* __restrict__ binCur,
                                                 const u32* __restrict__ binbuf,
                                                 int* __restrict__ cnt) {
    __shared__ int hist[RSZ2];
    const int b = blockIdx.x;
    const int t = threadIdx.x;
    for (int i = t; i < RSZ2; i += 1024) hist[i] = 0;
    __syncthreads();
    const int n = min(binCur[b], BINCAP);
    const u32* bin = binbuf + (size_t)b * BINCAP;
    for (int i = t; i < n; i += 1024)
        atomicAdd(&hist[bin[i] & 1023u], 1);
    __syncthreads();
    for (int i = t; i < RSZ2; i += 1024) {
        const int idx = b * RSZ2 + i;
        if (idx < NN) cnt[idx] = hist[i];
    }
}

__global__ void k_scan1(const int* __restrict__ cnt, int* __restrict__ rp,
                        int* __restrict__ tot) {
    __shared__ int lds[256];
    const int t    = threadIdx.x;
    const int base = blockIdx.x * SCAN_CHUNK + t * 4;
    int v[4];
#pragma unroll
    for (int i = 0; i < 4; ++i) v[i] = (base + i < NN) ? cnt[base + i] : 0;
    const int s = v[0] + v[1] + v[2] + v[3];
    lds[t] = s;
    __syncthreads();
    int val = s;
    for (int off = 1; off < 256; off <<= 1) {
        int other = (t >= off) ? lds[t - off] : 0;
        __syncthreads();
        val += other;
        lds[t] = val;
        __syncthreads();
    }
    int e = val - s; // exclusive prefix within block
#pragma unroll
    for (int i = 0; i < 4; ++i) {
        if (base + i < NN) rp[base + i] = e;
        e += v[i];
    }
    if (t == 255) tot[blockIdx.x] = val;
}

// parallel scan over the 98 block totals
__global__ void k_scan2(int* __restrict__ tot, int* __restrict__ rp) {
    __shared__ int l[128];
    const int t = threadIdx.x;
    const int v = (t < SCAN_BLOCKS) ? tot[t] : 0;
    l[t] = v;
    __syncthreads();
    int val = v;
    for (int off = 1; off < 128; off <<= 1) {
        const int o = (t >= off) ? l[t - off] : 0;
        __syncthreads();
        val += o;
        l[t] = val;
        __syncthreads();
    }
    if (t < SCAN_BLOCKS) tot[t] = val - v; // exclusive
    if (t == 127) rp[NN] = val;            // total == NE
}

// add block offsets
__global__ void k_scan3(int* __restrict__ rp, const int* __restrict__ tot) {
    int idx = blockIdx.x * 256 + threadIdx.x;
    if (idx < NN) rp[idx] += tot[idx >> 10];
}

// one block per range: LDS cursors seeded from rp, exclusive contiguous col writes
__global__ __launch_bounds__(1024) void k_fillL(const int* __restrict__ binCur,
                                                const u32* __restrict__ binbuf,
                                                const int* __restrict__ rp,
                                                int* __restrict__ col) {
    __shared__ int cur[RSZ2];
    const int b = blockIdx.x;
    const int t = threadIdx.x;
    for (int i = t; i < RSZ2; i += 1024) {
        const int idx = b * RSZ2 + i;
        cur[i] = (idx < NN) ? rp[idx] : 0;
    }
    __syncthreads();
    const int n = min(binCur[b], BINCAP);
    const u32* bin = binbuf + (size_t)b * BINCAP;
    for (int i = t; i < n; i += 1024) {
        const u32 e = bin[i];
        col[atomicAdd(&cur[e & 1023u], 1)] = (int)(e >> 10);
    }
}

// ---------------- weight prep: WT[n][k] = bf16(W[k][n]), 7 matrices ----------------

struct WTArgs { const float* w[7]; u16* o[7]; };

__global__ void k_wt(WTArgs a) {
    const int m = blockIdx.y;   // which matrix
    const int n = blockIdx.x;   // output row = W column
    const int k = threadIdx.x;  // 128
    a.o[m][n * HD + k] = f2bf(a.w[m][k * HD + n]);
}

// ---------------- mean aggregation: slice-per-XCD, one lane per (node, 16B chunk) ----------------

__device__ inline void acc8(float* a, u32x4 v) {
    a[0] += bflo(v.x); a[1] += bfhi(v.x);
    a[2] += bflo(v.y); a[3] += bfhi(v.y);
    a[4] += bflo(v.z); a[5] += bfhi(v.z);
    a[6] += bflo(v.w); a[7] += bfhi(v.w);
}

__global__ __launch_bounds__(256) void k_agg(const u16* __restrict__ h,
                                             const int* __restrict__ rp,
                                             const int* __restrict__ col,
                                             u16* __restrict__ mean) {
    const int s    = blockIdx.x & 15;                       // chunk slice -> XCD s%8
    const int node = (blockIdx.x >> 4) * 256 + threadIdx.x;
    if (node >= NN) return;
    const int r0 = rp[node], r1 = rp[node + 1];
    const u32x4* hs = reinterpret_cast<const u32x4*>(h) + (size_t)s * NN;
    float a[8];
#pragma unroll
    for (int i = 0; i < 8; ++i) a[i] = 0.f;
    int e = r0;
    for (; e + 4 <= r1; e += 4) {
        const int s0 = col[e], s1 = col[e + 1], s2 = col[e + 2], s3 = col[e + 3];
        const u32x4 v0 = hs[s0];
        const u32x4 v1 = hs[s1];
        const u32x4 v2 = hs[s2];
        const u32x4 v3 = hs[s3];
        acc8(a, v0); acc8(a, v1); acc8(a, v2); acc8(a, v3);
    }
    for (; e < r1; ++e) acc8(a, hs[col[e]]);
    const float inv = 1.0f / fmaxf((float)(r1 - r0), 1.0f);
    u32x4 o;
    o.x = pack2(a[0] * inv, a[1] * inv);
    o.y = pack2(a[2] * inv, a[3] * inv);
    o.z = pack2(a[4] * inv, a[5] * inv);
    o.w = pack2(a[6] * inv, a[7] * inv);
    // NT store: don't evict the L2-resident h slice with mean write-allocates
    __builtin_nontemporal_store(o, reinterpret_cast<u32x4*>(mean) + (size_t)s * NN + node);
}

// ---------------- MFMA GEMM (tiled activations): out = A1@W1 (+ A2@W2) + bias ----------------
// 256 threads = 4 waves; block tile 128x128; wave tile 32x128 (2 row-frags).
// Weights staged in LDS (XOR-swizzled); pass's 8 A-frag loads hoisted.
// A (bf16) and D use the chunk-tiled layout; A1F32 path reads row-major fp32 x.

template <int A1F32, int RELU, int STATS>
__global__ __launch_bounds__(256) void k_mgemm(
    const void* __restrict__ A1p, const u16* __restrict__ W1T,
    const u16* __restrict__ A2, const u16* __restrict__ W2T,
    const float* __restrict__ bias, u16* __restrict__ out,
    float* __restrict__ stats)
{
    __shared__ u32x4 Wlds[2048]; // 32 KB: one 128x128 bf16 weight matrix, swizzled
    const int t    = threadIdx.x;
    const int wv   = t >> 6;
    const int lane = t & 63;
    const int lid  = lane & 15;   // A-row / B-col / D-col within tile
    const int kseg = lane >> 4;   // 0..3
    const int row0 = blockIdx.x * 128 + wv * 32;   // wave's 32-row tile

    f32x4 acc[2][8];
#pragma unroll
    for (int rf = 0; rf < 2; ++rf)
#pragma unroll
        for (int c = 0; c < 8; ++c) acc[rf][c] = (f32x4){0.f, 0.f, 0.f, 0.f};

    int  ar[2];
    bool rok[2];
#pragma unroll
    for (int rf = 0; rf < 2; ++rf) {
        ar[rf]  = row0 + rf * 16 + lid;
        rok[rf] = ar[rf] < NN;
    }

    for (int pass = 0; pass < 2; ++pass) {
        if (pass == 1 && A2 == nullptr) break;
        const u16* WT = pass ? W2T : W1T;
        if (pass) __syncthreads();          // all waves done reading pass-0 weights
#pragma unroll
        for (int i = 0; i < 8; ++i) {
            const int g   = t + 256 * i;    // 0..2047 (16B chunks)
            const int row = g >> 4;
            const int ch  = g & 15;
            Wlds[row * 16 + (ch ^ (row & 7))] = reinterpret_cast<const u32x4*>(WT)[g];
        }
        // hoist all 8 A-fragment loads of this pass (2 rf x 4 kk)
        bf16x8 af[2][4];
        if (A1F32 && pass == 0) {
            const float* A = (const float*)A1p;
#pragma unroll
            for (int rf = 0; rf < 2; ++rf)
#pragma unroll
                for (int kk = 0; kk < 4; ++kk) {
                    const int kof = kk * 32 + kseg * 8;
                    if (rok[rf]) {
                        const float4 f0 = *reinterpret_cast<const float4*>(&A[(size_t)ar[rf] * HD + kof]);
                        const float4 f1 = *reinterpret_cast<const float4*>(&A[(size_t)ar[rf] * HD + kof + 4]);
                        af[rf][kk][0] = (short)f2bf(f0.x); af[rf][kk][1] = (short)f2bf(f0.y);
                        af[rf][kk][2] = (short)f2bf(f0.z); af[rf][kk][3] = (short)f2bf(f0.w);
                        af[rf][kk][4] = (short)f2bf(f1.x); af[rf][kk][5] = (short)f2bf(f1.y);
                        af[rf][kk][6] = (short)f2bf(f1.z); af[rf][kk][7] = (short)f2bf(f1.w);
                    } else {
                        af[rf][kk] = (bf16x8)0;
                    }
                }
        } else {
            const u16* A = pass ? A2 : (const u16*)A1p;
#pragma unroll
            for (int rf = 0; rf < 2; ++rf)
#pragma unroll
                for (int kk = 0; kk < 4; ++kk) {
                    const int chunk = kk * 4 + kseg;      // tiled: A[chunk][node][8]
                    af[rf][kk] = rok[rf]
                        ? *reinterpret_cast<const bf16x8*>(&A[((size_t)chunk * NN + ar[rf]) * 8])
                        : (bf16x8)0;
                }
        }
        __syncthreads();                    // weights staged
#pragma unroll
        for (int kk = 0; kk < 4; ++kk) {
#pragma unroll
            for (int c = 0; c < 8; ++c) {
                const int brow = c * 16 + lid;
                const bf16x8 bf = *reinterpret_cast<const bf16x8*>(
                    &Wlds[brow * 16 + ((kk * 4 + kseg) ^ (lid & 7))]);
#pragma unroll
                for (int rf = 0; rf < 2; ++rf)
                    acc[rf][c] = __builtin_amdgcn_mfma_f32_16x16x32_bf16(af[rf][kk], bf, acc[rf][c], 0, 0, 0);
            }
        }
    }

    float bv[8];
#pragma unroll
    for (int c = 0; c < 8; ++c) bv[c] = bias[c * 16 + lid];

    float sv[8], qv[8];
#pragma unroll
    for (int c = 0; c < 8; ++c) { sv[c] = 0.f; qv[c] = 0.f; }

#pragma unroll
    for (int rf = 0; rf < 2; ++rf) {
#pragma unroll
        for (int c = 0; c < 8; ++c) {
            const int colc  = c * 16 + lid;
            const int chunk = colc >> 3;
            const int w8    = colc & 7;
#pragma unroll
            for (int j = 0; j < 4; ++j) {
                const int rrow = row0 + rf * 16 + kseg * 4 + j;
                if (rrow < NN) {
                    float o = acc[rf][c][j] + bv[c];
                    if (RELU) o = fmaxf(o, 0.f);
                    out[((size_t)chunk * NN + rrow) * 8 + w8] = f2bf(o);
                    sv[c] += o;
                    qv[c] += o * o;
                }
            }
        }
    }

    if constexpr (STATS) {
        __shared__ float ls[4][HD], lq[4][HD];
#pragma unroll
        for (int c = 0; c < 8; ++c) {
            sv[c] += __shfl_xor(sv[c], 16);
            sv[c] += __shfl_xor(sv[c], 32);
            qv[c] += __shfl_xor(qv[c], 16);
            qv[c] += __shfl_xor(qv[c], 32);
        }
        if (lane < 16) {
#pragma unroll
            for (int c = 0; c < 8; ++c) {
                ls[wv][c * 16 + lid] = sv[c];
                lq[wv][c * 16 + lid] = qv[c];
            }
        }
        __syncthreads();
        if (t < HD) {
            const float s = (ls[0][t] + ls[1][t]) + (ls[2][t] + ls[3][t]);
            atomicAdd(&stats[t], s);
        } else {
            const int j = t - HD;
            const float q = (lq[0][j] + lq[1][j]) + (lq[2][j] + lq[3][j]);
            atomicAdd(&stats[HD + j], q);
        }
    }
}

// ---------------- BN-finalize + relu + residual (tiled; grid = (nodes/256, 16 chunks)) ----------------

__global__ __launch_bounds__(256) void k_apply(
    const u16* __restrict__ outb, const float* __restrict__ stats,
    const float* __restrict__ g, const float* __restrict__ bt,
    u16* __restrict__ hb)
{
    const int chunk = blockIdx.y;
    const int node  = blockIdx.x * 256 + threadIdx.x;
    if (node >= NN) return;
    const int j0 = chunk * 8;
    const float invn = 1.0f / (float)NN;
    float sc[8], sh[8];
#pragma unroll
    for (int i = 0; i < 8; ++i) {
        const float mean = stats[j0 + i] * invn;
        const float var  = stats[HD + j0 + i] * invn - mean * mean;
        const float s    = g[j0 + i] * rsqrtf(var + EPSI);
        sc[i] = s;
        sh[i] = bt[j0 + i] - mean * s;
    }
    const size_t idx = (size_t)chunk * NN + node;
    const u32x4 o  = reinterpret_cast<const u32x4*>(outb)[idx];
    const u32x4 hv = reinterpret_cast<const u32x4*>(hb)[idx];
    const u32 ov[4] = {o.x, o.y, o.z, o.w};
    const u32 hu[4] = {hv.x, hv.y, hv.z, hv.w};
    u32x4 res;
#pragma unroll
    for (int i = 0; i < 4; ++i) {
        const float r0 = fmaxf(bflo(ov[i]) * sc[i * 2 + 0] + sh[i * 2 + 0], 0.f) + bflo(hu[i]);
        const float r1 = fmaxf(bfhi(ov[i]) * sc[i * 2 + 1] + sh[i * 2 + 1], 0.f) + bfhi(hu[i]);
        res[i] = pack2(r0, r1);
    }
    reinterpret_cast<u32x4*>(hb)[idx] = res;
}

// ---------------- classifier: one wave per row (tiled h) ----------------

__global__ void k_cls(const u16* __restrict__ h, const float* __restrict__ w,
                      const float* __restrict__ b, float* __restrict__ out) {
    const int lane = threadIdx.x & 63;
    const int i = (int)((blockIdx.x * 256 + threadIdx.x) >> 6);
    if (i >= NN) return;
    const int chunk = lane >> 2;
    const int off   = (lane & 3) * 2;     // cols 2*lane, 2*lane+1
    const u32 v = *reinterpret_cast<const u32*>(&h[((size_t)chunk * NN + i) * 8 + off]);
    const float h0 = bflo(v), h1 = bfhi(v);
    const float4 wv = *reinterpret_cast<const float4*>(&w[lane * 4]); // rows 2l,2l+1 of [128,2]
    float a0 = h0 * wv.x + h1 * wv.z;
    float a1 = h0 * wv.y + h1 * wv.w;
#pragma unroll
    for (int off2 = 32; off2 > 0; off2 >>= 1) {
        a0 += __shfl_xor(a0, off2);
        a1 += __shfl_xor(a1, off2);
    }
    if (lane == 0) {
        out[(size_t)i * 2 + 0] = a0 + b[0];
        out[(size_t)i * 2 + 1] = a1 + b[1];
    }
}

// ---------------- launch ----------------

extern "C" void kernel_launch(void* const* d_in, const int* in_sizes, int n_in,
                              void* d_out, int out_size, void* d_ws, size_t ws_size,
                              hipStream_t stream) {
    const float* x     = (const float*)d_in[0];
    const int*   ei    = (const int*)d_in[1];
    const float* in_w  = (const float*)d_in[2];
    const float* in_b  = (const float*)d_in[3];
    const float* cls_w = (const float*)d_in[4];
    const float* cls_b = (const float*)d_in[5];
    const float* blk_w[3][5]; // lw, lb, rw, g, bt
    for (int bidx = 0; bidx < 3; ++bidx)
        for (int k = 0; k < 5; ++k)
            blk_w[bidx][k] = (const float*)d_in[6 + bidx * 5 + k];

    const int* src = ei;
    const int* dst = ei + NE;

    // workspace layout (~59 MB). binbuf (8.4 MB) overlays tmp (CSR phase only).
    size_t off = 0;
    auto alloc = [&](size_t bytes) {
        void* p = (char*)d_ws + off;
        off += (bytes + 255) & ~(size_t)255;
        return p;
    };
    u16*   h      = (u16*)alloc((size_t)NN * HD * 2);   // 25.6 MB, chunk-tiled
    u16*   tmp    = (u16*)alloc((size_t)NN * HD * 2);   // 25.6 MB (binbuf, then mean/out, tiled)
    int*   rp     = (int*)alloc((size_t)(NN + 1) * 4);
    int*   cnt    = (int*)alloc((size_t)NN * 4);        // written non-atomically, no memset
    int*   col    = (int*)alloc((size_t)NE * 4);        // 6.4 MB
    int*   stot   = (int*)alloc((size_t)SCAN_BLOCKS * 4);
    u16*   wtb    = (u16*)alloc((size_t)7 * HD * HD * 2); // 224 KB transposed bf16 weights
    const size_t off_z = off;
    float* stats  = (float*)alloc((size_t)3 * 256 * 4);
    int*   binCur = (int*)alloc((size_t)NRANGE * 4);
    const size_t zspan = off - off_z;                   // stats+binCur, one memset
    u32*   binbuf = (u32*)tmp;                          // 128 bins x 16384 u32 = 8.4 MB
    (void)ws_size; (void)n_in; (void)in_sizes; (void)out_size;

    (void)hipMemsetAsync(stats, 0, zspan, stream);

    // transposed bf16 weights: [0]=in_w, then per block lw, rw
    WTArgs wa;
    wa.w[0] = in_w;
    for (int bidx = 0; bidx < 3; ++bidx) {
        wa.w[1 + bidx * 2] = blk_w[bidx][0]; // lw
        wa.w[2 + bidx * 2] = blk_w[bidx][2]; // rw
    }
    for (int m = 0; m < 7; ++m) wa.o[m] = wtb + (size_t)m * HD * HD;
    k_wt<<<dim3(HD, 7), HD, 0, stream>>>(wa);

    // CSR build: partition once, LDS-local count + fill (no per-edge global atomics)
    k_part<<<PART_GRID, 256, 0, stream>>>(src, dst, binCur, binbuf);
    k_countL<<<NRANGE, 1024, 0, stream>>>(binCur, binbuf, cnt);
    k_scan1<<<SCAN_BLOCKS, 256, 0, stream>>>(cnt, rp, stot);
    k_scan2<<<1, 128, 0, stream>>>(stot, rp);
    k_scan3<<<(NN + 255) / 256, 256, 0, stream>>>(rp, stot);
    k_fillL<<<NRANGE, 1024, 0, stream>>>(binCur, binbuf, rp, col);

    const int  nodeb      = (NN + 255) / 256;  // 391
    const int  gemm_grid  = (NN + 127) / 128;  // 782
    const int  agg_grid   = nodeb * 16;        // 6256: slice = blockIdx % 16
    const dim3 apply_grid(nodeb, 16);

    // input layer: h = relu(x @ in_w + in_b)
    k_mgemm<1, 1, 0><<<gemm_grid, 256, 0, stream>>>(x, wtb, nullptr, nullptr, in_b, h, nullptr);

    for (int bidx = 0; bidx < 3; ++bidx) {
        const u16* lwT = wtb + (size_t)(1 + bidx * 2) * HD * HD;
        const u16* rwT = wtb + (size_t)(2 + bidx * 2) * HD * HD;
        const float* lb = blk_w[bidx][1];
        const float* g  = blk_w[bidx][3];
        const float* bt = blk_w[bidx][4];
        float* st = stats + bidx * 256;
        k_agg<<<agg_grid, 256, 0, stream>>>(h, rp, col, tmp);
        k_mgemm<0, 0, 1><<<gemm_grid, 256, 0, stream>>>(tmp, lwT, h, rwT, lb, tmp, st);
        k_apply<<<apply_grid, 256, 0, stream>>>(tmp, st, g, bt, h);
    }

    k_cls<<<(NN + 3) / 4, 256, 0, stream>>>(h, cls_w, cls_b, (float*)d_out);
}

// Round 12
// 397.349 us; speedup vs baseline: 1.6819x; 1.6819x over previous
//
#include <hip/hip_runtime.h>

#define NN 100000
#define NE 1600000
#define HD 128
#define EPSI 1e-5f

using u32 = unsigned int;
using u16 = unsigned short;

typedef short bf16x8 __attribute__((ext_vector_type(8)));
typedef float f32x4  __attribute__((ext_vector_type(4)));
typedef u32   u32x4  __attribute__((ext_vector_type(4)));

constexpr int SCAN_CHUNK  = 1024;
constexpr int SCAN_BLOCKS = (NN + SCAN_CHUNK - 1) / SCAN_CHUNK; // 98
constexpr int NRANGE      = 128;                  // dst ranges (one fill/count block each)
constexpr int RSZ2        = 784;                  // nodes per range (128*784 >= NN), < 1024 for packing
constexpr int BINCAP      = 16384;                // u32 slots per bin (mean 12544)
constexpr int PART_CHUNK4 = 1024;                 // int4s per block in k_part (4096 edges)
constexpr int PART_GRID   = (NE / 4 + PART_CHUNK4 - 1) / PART_CHUNK4; // 391

// ---- bf16 helpers (storage bf16, arithmetic fp32) ----
__device__ inline float bflo(u32 u) { return __uint_as_float(u << 16); }
__device__ inline float bfhi(u32 u) { return __uint_as_float(u & 0xFFFF0000u); }
__device__ inline u16 f2bf(float f) {
    u32 u = __float_as_uint(f);
    u += 0x7FFFu + ((u >> 16) & 1u); // RNE
    return (u16)(u >> 16);
}
__device__ inline u32 pack2(float a, float b) {
    return (u32)f2bf(a) | ((u32)f2bf(b) << 16);
}

// ---------------- CSR build: single-read 128-bin partition (u32-packed), LDS-ranked fill ----------------

__global__ __launch_bounds__(256) void k_part(const int* __restrict__ src,
                                              const int* __restrict__ dst,
                                              int* __restrict__ binCur,
                                              u32* __restrict__ binbuf) {
    __shared__ int hist[NRANGE], base[NRANGE], curs[NRANGE];
    const int t  = threadIdx.x;
    const int c0 = blockIdx.x * PART_CHUNK4;
    if (t < NRANGE) { hist[t] = 0; curs[t] = 0; }
    __syncthreads();

    int4 ds[4], ss[4];
    bool ok[4];
#pragma unroll
    for (int i = 0; i < 4; ++i) {
        const int c = c0 + t + 256 * i;
        ok[i] = c < NE / 4;
        if (ok[i]) {
            ds[i] = reinterpret_cast<const int4*>(dst)[c];
            ss[i] = reinterpret_cast<const int4*>(src)[c];
        }
    }
#pragma unroll
    for (int i = 0; i < 4; ++i) {
        if (ok[i]) {
            atomicAdd(&hist[ds[i].x / RSZ2], 1);
            atomicAdd(&hist[ds[i].y / RSZ2], 1);
            atomicAdd(&hist[ds[i].z / RSZ2], 1);
            atomicAdd(&hist[ds[i].w / RSZ2], 1);
        }
    }
    __syncthreads();
    if (t < NRANGE && hist[t] > 0) base[t] = atomicAdd(&binCur[t], hist[t]);
    __syncthreads();

#pragma unroll
    for (int i = 0; i < 4; ++i) {
        if (ok[i]) {
            const int d[4] = {ds[i].x, ds[i].y, ds[i].z, ds[i].w};
            const int s[4] = {ss[i].x, ss[i].y, ss[i].z, ss[i].w};
#pragma unroll
            for (int j = 0; j < 4; ++j) {
                const int r  = d[j] / RSZ2;
                const int ld = d[j] - r * RSZ2;      // < 1024
                const int p  = base[r] + atomicAdd(&curs[r], 1);
                if (p < BINCAP)
                    binbuf[(size_t)r * BINCAP + p] = ((u32)s[j] << 10) | (u32)ld;
            }
        }
    }
}

// one block per range: per-node counts via LDS histogram, non-atomic cnt write
__global__ __launch_bounds__(1024) void k_countL(const int* __restrict__ binCur,
                                                 const u32* __restrict__ binbuf,
                                                 int* __restrict__ cnt) {
    __shared__ int hist[RSZ2];
    const int b = blockIdx.x;
    const int t = threadIdx.x;
    for (int i = t; i < RSZ2; i += 1024) hist[i] = 0;
    __syncthreads();
    const int n = min(binCur[b], BINCAP);
    const u32* bin = binbuf + (size_t)b * BINCAP;
    for (int i = t; i < n; i += 1024)
        atomicAdd(&hist[bin[i] & 1023u], 1);
    __syncthreads();
    for (int i = t; i < RSZ2; i += 1024) {
        const int idx = b * RSZ2 + i;
        if (idx < NN) cnt[idx] = hist[i];
    }
}

__global__ void k_scan1(const int* __restrict__ cnt, int* __restrict__ rp,
                        int* __restrict__ tot) {
    __shared__ int lds[256];
    const int t    = threadIdx.x;
    const int base = blockIdx.x * SCAN_CHUNK + t * 4;
    int v[4];
#pragma unroll
    for (int i = 0; i < 4; ++i) v[i] = (base + i < NN) ? cnt[base + i] : 0;
    const int s = v[0] + v[1] + v[2] + v[3];
    lds[t] = s;
    __syncthreads();
    int val = s;
    for (int off = 1; off < 256; off <<= 1) {
        int other = (t >= off) ? lds[t - off] : 0;
        __syncthreads();
        val += other;
        lds[t] = val;
        __syncthreads();
    }
    int e = val - s; // exclusive prefix within block
#pragma unroll
    for (int i = 0; i < 4; ++i) {
        if (base + i < NN) rp[base + i] = e;
        e += v[i];
    }
    if (t == 255) tot[blockIdx.x] = val;
}

// parallel scan over the 98 block totals
__global__ void k_scan2(int* __restrict__ tot, int* __restrict__ rp) {
    __shared__ int l[128];
    const int t = threadIdx.x;
    const int v = (t < SCAN_BLOCKS) ? tot[t] : 0;
    l[t] = v;
    __syncthreads();
    int val = v;
    for (int off = 1; off < 128; off <<= 1) {
        const int o = (t >= off) ? l[t - off] : 0;
        __syncthreads();
        val += o;
        l[t] = val;
        __syncthreads();
    }
    if (t < SCAN_BLOCKS) tot[t] = val - v; // exclusive
    if (t == 127) rp[NN] = val;            // total == NE
}

// add block offsets
__global__ void k_scan3(int* __restrict__ rp, const int* __restrict__ tot) {
    int idx = blockIdx.x * 256 + threadIdx.x;
    if (idx < NN) rp[idx] += tot[idx >> 10];
}

// one block per range: LDS cursors seeded from rp, exclusive contiguous col writes
__global__ __launch_bounds__(1024) void k_fillL(const int* __restrict__ binCur,
                                                const u32* __restrict__ binbuf,
                                                const int* __restrict__ rp,
                                                int* __restrict__ col) {
    __shared__ int cur[RSZ2];
    const int b = blockIdx.x;
    const int t = threadIdx.x;
    for (int i = t; i < RSZ2; i += 1024) {
        const int idx = b * RSZ2 + i;
        cur[i] = (idx < NN) ? rp[idx] : 0;
    }
    __syncthreads();
    const int n = min(binCur[b], BINCAP);
    const u32* bin = binbuf + (size_t)b * BINCAP;
    for (int i = t; i < n; i += 1024) {
        const u32 e = bin[i];
        col[atomicAdd(&cur[e & 1023u], 1)] = (int)(e >> 10);
    }
}

// ---------------- weight prep: WT[n][k] = bf16(W[k][n]), 7 matrices ----------------

struct WTArgs { const float* w[7]; u16* o[7]; };

__global__ void k_wt(WTArgs a) {
    const int m = blockIdx.y;   // which matrix
    const int n = blockIdx.x;   // output row = W column
    const int k = threadIdx.x;  // 128
    a.o[m][n * HD + k] = f2bf(a.w[m][k * HD + n]);
}

// ---------------- mean aggregation: one node per wave, 4-group edge striping, 4x unroll ----------------
// (round-9 verified version: full-row gathers use whole cache lines, L3 absorbs)

__device__ inline void acc8(float* a, u32x4 v) {
    a[0] += bflo(v.x); a[1] += bfhi(v.x);
    a[2] += bflo(v.y); a[3] += bfhi(v.y);
    a[4] += bflo(v.z); a[5] += bfhi(v.z);
    a[6] += bflo(v.w); a[7] += bfhi(v.w);
}

__global__ __launch_bounds__(256) void k_agg(const u16* __restrict__ h,
                                             const int* __restrict__ rp,
                                             const int* __restrict__ col,
                                             u16* __restrict__ mean) {
    const int lane = threadIdx.x & 63;
    const int node = blockIdx.x * 4 + (threadIdx.x >> 6); // NN % 4 == 0
    const int grp  = lane >> 4;   // 0..3: edge stripe
    const int li   = lane & 15;   // 16B chunk within row
    const int r0 = rp[node], r1 = rp[node + 1];
    const size_t lof = (size_t)li * 8;
    float a[8];
#pragma unroll
    for (int i = 0; i < 8; ++i) a[i] = 0.f;
    int e = r0 + grp;
    for (; e + 12 < r1; e += 16) { // 4x unroll: 16 outstanding gathers per wave
        const int s0 = col[e], s1 = col[e + 4], s2 = col[e + 8], s3 = col[e + 12];
        const u32x4 v0 = *reinterpret_cast<const u32x4*>(&h[(size_t)s0 * HD + lof]);
        const u32x4 v1 = *reinterpret_cast<const u32x4*>(&h[(size_t)s1 * HD + lof]);
        const u32x4 v2 = *reinterpret_cast<const u32x4*>(&h[(size_t)s2 * HD + lof]);
        const u32x4 v3 = *reinterpret_cast<const u32x4*>(&h[(size_t)s3 * HD + lof]);
        acc8(a, v0); acc8(a, v1); acc8(a, v2); acc8(a, v3);
    }
    for (; e < r1; e += 4) {
        const u32x4 v = *reinterpret_cast<const u32x4*>(&h[(size_t)col[e] * HD + lof]);
        acc8(a, v);
    }
    // combine the 4 groups (lanes l, l+16, l+32, l+48)
#pragma unroll
    for (int i = 0; i < 8; ++i) {
        a[i] += __shfl_xor(a[i], 16);
        a[i] += __shfl_xor(a[i], 32);
    }
    if (lane < 16) {
        const float inv = 1.0f / fmaxf((float)(r1 - r0), 1.0f);
        u32x4 o;
        o.x = pack2(a[0] * inv, a[1] * inv);
        o.y = pack2(a[2] * inv, a[3] * inv);
        o.z = pack2(a[4] * inv, a[5] * inv);
        o.w = pack2(a[6] * inv, a[7] * inv);
        *reinterpret_cast<u32x4*>(&mean[(size_t)node * HD + lof]) = o;
    }
}

// ---------------- MFMA GEMM: out = A1@W1 (+ A2@W2) + bias ----------------
// 256 threads = 4 waves; block tile 128x128; wave tile 32x128 (2 row-frags).
// W1 staged to LDS (XOR-swizzled); W2 reg-prefetched at start, ds_written
// after pass-0 (T14 split). ALL A-fragments (both passes) hoisted up front:
// one latency round for the whole kernel.

template <int A1F32, int RELU, int STATS>
__global__ __launch_bounds__(256) void k_mgemm(
    const void* __restrict__ A1p, const u16* __restrict__ W1T,
    const u16* __restrict__ A2, const u16* __restrict__ W2T,
    const float* __restrict__ bias, u16* __restrict__ out,
    float* __restrict__ stats)
{
    __shared__ u32x4 Wlds[2048]; // 32 KB: one 128x128 bf16 weight matrix, swizzled
    const int t    = threadIdx.x;
    const int wv   = t >> 6;
    const int lane = t & 63;
    const int lid  = lane & 15;   // A-row / B-col / D-col within tile
    const int kseg = lane >> 4;   // 0..3
    const int row0 = blockIdx.x * 128 + wv * 32;   // wave's 32-row tile

    f32x4 acc[2][8];
#pragma unroll
    for (int rf = 0; rf < 2; ++rf)
#pragma unroll
        for (int c = 0; c < 8; ++c) acc[rf][c] = (f32x4){0.f, 0.f, 0.f, 0.f};

    int  ar[2];
    bool rok[2];
#pragma unroll
    for (int rf = 0; rf < 2; ++rf) {
        ar[rf]  = row0 + rf * 16 + lid;
        rok[rf] = ar[rf] < NN;
    }

    // --- issue everything up front: W1->LDS, W2->regs, A-frags (both passes) ---
#pragma unroll
    for (int i = 0; i < 8; ++i) {
        const int g   = t + 256 * i;    // 0..2047 (16B chunks)
        const int row = g >> 4;
        const int ch  = g & 15;
        Wlds[row * 16 + (ch ^ (row & 7))] = reinterpret_cast<const u32x4*>(W1T)[g];
    }
    u32x4 wreg[8];
    if (A2 != nullptr) {
#pragma unroll
        for (int i = 0; i < 8; ++i)
            wreg[i] = reinterpret_cast<const u32x4*>(W2T)[t + 256 * i];
    }

    bf16x8 af1[2][4], af2[2][4];
    if (A1F32) {
        const float* A = (const float*)A1p;
#pragma unroll
        for (int rf = 0; rf < 2; ++rf)
#pragma unroll
            for (int kk = 0; kk < 4; ++kk) {
                const int kof = kk * 32 + kseg * 8;
                if (rok[rf]) {
                    const float4 f0 = *reinterpret_cast<const float4*>(&A[(size_t)ar[rf] * HD + kof]);
                    const float4 f1 = *reinterpret_cast<const float4*>(&A[(size_t)ar[rf] * HD + kof + 4]);
                    af1[rf][kk][0] = (short)f2bf(f0.x); af1[rf][kk][1] = (short)f2bf(f0.y);
                    af1[rf][kk][2] = (short)f2bf(f0.z); af1[rf][kk][3] = (short)f2bf(f0.w);
                    af1[rf][kk][4] = (short)f2bf(f1.x); af1[rf][kk][5] = (short)f2bf(f1.y);
                    af1[rf][kk][6] = (short)f2bf(f1.z); af1[rf][kk][7] = (short)f2bf(f1.w);
                } else {
                    af1[rf][kk] = (bf16x8)0;
                }
            }
    } else {
        const u16* A = (const u16*)A1p;
#pragma unroll
        for (int rf = 0; rf < 2; ++rf)
#pragma unroll
            for (int kk = 0; kk < 4; ++kk) {
                const int kof = kk * 32 + kseg * 8;
                af1[rf][kk] = rok[rf]
                    ? *reinterpret_cast<const bf16x8*>(&A[(size_t)ar[rf] * HD + kof])
                    : (bf16x8)0;
            }
    }
    if (A2 != nullptr) {
#pragma unroll
        for (int rf = 0; rf < 2; ++rf)
#pragma unroll
            for (int kk = 0; kk < 4; ++kk) {
                const int kof = kk * 32 + kseg * 8;
                af2[rf][kk] = rok[rf]
                    ? *reinterpret_cast<const bf16x8*>(&A2[(size_t)ar[rf] * HD + kof])
                    : (bf16x8)0;
            }
    }

    __syncthreads();                    // W1 staged
    // pass 0 MFMA
#pragma unroll
    for (int kk = 0; kk < 4; ++kk) {
#pragma unroll
        for (int c = 0; c < 8; ++c) {
            const int brow = c * 16 + lid;
            const bf16x8 bf = *reinterpret_cast<const bf16x8*>(
                &Wlds[brow * 16 + ((kk * 4 + kseg) ^ (lid & 7))]);
#pragma unroll
            for (int rf = 0; rf < 2; ++rf)
                acc[rf][c] = __builtin_amdgcn_mfma_f32_16x16x32_bf16(af1[rf][kk], bf, acc[rf][c], 0, 0, 0);
        }
    }

    if (A2 != nullptr) {
        __syncthreads();                // all waves done reading W1
#pragma unroll
        for (int i = 0; i < 8; ++i) {
            const int g   = t + 256 * i;
            const int row = g >> 4;
            const int ch  = g & 15;
            Wlds[row * 16 + (ch ^ (row & 7))] = wreg[i];
        }
        __syncthreads();                // W2 staged (no global latency here)
#pragma unroll
        for (int kk = 0; kk < 4; ++kk) {
#pragma unroll
            for (int c = 0; c < 8; ++c) {
                const int brow = c * 16 + lid;
                const bf16x8 bf = *reinterpret_cast<const bf16x8*>(
                    &Wlds[brow * 16 + ((kk * 4 + kseg) ^ (lid & 7))]);
#pragma unroll
                for (int rf = 0; rf < 2; ++rf)
                    acc[rf][c] = __builtin_amdgcn_mfma_f32_16x16x32_bf16(af2[rf][kk], bf, acc[rf][c], 0, 0, 0);
            }
        }
    }

    float bv[8];
#pragma unroll
    for (int c = 0; c < 8; ++c) bv[c] = bias[c * 16 + lid];

    float sv[8], qv[8];
#pragma unroll
    for (int c = 0; c < 8; ++c) { sv[c] = 0.f; qv[c] = 0.f; }

#pragma unroll
    for (int rf = 0; rf < 2; ++rf) {
#pragma unroll
        for (int c = 0; c < 8; ++c) {
            const int colc = c * 16 + lid;
#pragma unroll
            for (int j = 0; j < 4; ++j) {
                const int rrow = row0 + rf * 16 + kseg * 4 + j;
                if (rrow < NN) {
                    float o = acc[rf][c][j] + bv[c];
                    if (RELU) o = fmaxf(o, 0.f);
                    out[(size_t)rrow * HD + colc] = f2bf(o);
                    sv[c] += o;
                    qv[c] += o * o;
                }
            }
        }
    }

    if constexpr (STATS) {
        __shared__ float ls[4][HD], lq[4][HD];
#pragma unroll
        for (int c = 0; c < 8; ++c) {
            sv[c] += __shfl_xor(sv[c], 16);
            sv[c] += __shfl_xor(sv[c], 32);
            qv[c] += __shfl_xor(qv[c], 16);
            qv[c] += __shfl_xor(qv[c], 32);
        }
        if (lane < 16) {
#pragma unroll
            for (int c = 0; c < 8; ++c) {
                ls[wv][c * 16 + lid] = sv[c];
                lq[wv][c * 16 + lid] = qv[c];
            }
        }
        __syncthreads();
        if (t < HD) {
            const float s = (ls[0][t] + ls[1][t]) + (ls[2][t] + ls[3][t]);
            atomicAdd(&stats[t], s);
        } else {
            const int j = t - HD;
            const float q = (lq[0][j] + lq[1][j]) + (lq[2][j] + lq[3][j]);
            atomicAdd(&stats[HD + j], q);
        }
    }
}

// ---------------- fused BN-finalize + relu + residual (+ classifier) ----------------
// thread covers 4 cols of one row; 32 threads per row.

template <int CLS>
__global__ __launch_bounds__(256) void k_apply(
    const u16* __restrict__ outb, const float* __restrict__ stats,
    const float* __restrict__ g, const float* __restrict__ bt,
    u16* __restrict__ hb, const float* __restrict__ cw,
    const float* __restrict__ cb, float* __restrict__ logits)
{
    const int t = threadIdx.x;
    const size_t idx4 = (size_t)blockIdx.x * 256 + t;
    const int j = (int)(idx4 & 31) * 4; // column base
    const float4 svv = *reinterpret_cast<const float4*>(&stats[j]);
    const float4 qvv = *reinterpret_cast<const float4*>(&stats[HD + j]);
    const float4 gv  = *reinterpret_cast<const float4*>(&g[j]);
    const float4 bv  = *reinterpret_cast<const float4*>(&bt[j]);
    const float invn = 1.0f / (float)NN;
    float sc[4], sh[4];
    {
        const float sa[4] = {svv.x, svv.y, svv.z, svv.w};
        const float qa[4] = {qvv.x, qvv.y, qvv.z, qvv.w};
        const float ga[4] = {gv.x, gv.y, gv.z, gv.w};
        const float ba[4] = {bv.x, bv.y, bv.z, bv.w};
#pragma unroll
        for (int i = 0; i < 4; ++i) {
            const float mean = sa[i] * invn;
            const float var  = qa[i] * invn - mean * mean;
            sc[i] = ga[i] * rsqrtf(var + EPSI);
            sh[i] = ba[i] - mean * sc[i];
        }
    }
    const uint2 o  = reinterpret_cast<const uint2*>(outb)[idx4];
    const uint2 hv = reinterpret_cast<const uint2*>(hb)[idx4];
    const float r0 = fmaxf(bflo(o.x) * sc[0] + sh[0], 0.f) + bflo(hv.x);
    const float r1 = fmaxf(bfhi(o.x) * sc[1] + sh[1], 0.f) + bfhi(hv.x);
    const float r2 = fmaxf(bflo(o.y) * sc[2] + sh[2], 0.f) + bflo(hv.y);
    const float r3 = fmaxf(bfhi(o.y) * sc[3] + sh[3], 0.f) + bfhi(hv.y);
    reinterpret_cast<uint2*>(hb)[idx4] = make_uint2(pack2(r0, r1), pack2(r2, r3));

    if constexpr (CLS) {
        const float4 w01 = *reinterpret_cast<const float4*>(&cw[j * 2]);
        const float4 w23 = *reinterpret_cast<const float4*>(&cw[j * 2 + 4]);
        float p0 = r0 * w01.x + r1 * w01.z + r2 * w23.x + r3 * w23.z;
        float p1 = r0 * w01.y + r1 * w01.w + r2 * w23.y + r3 * w23.w;
#pragma unroll
        for (int off = 1; off <= 16; off <<= 1) {
            p0 += __shfl_xor(p0, off);
            p1 += __shfl_xor(p1, off);
        }
        if ((t & 31) == 0) {
            const size_t row = idx4 >> 5;
            logits[row * 2 + 0] = p0 + cb[0];
            logits[row * 2 + 1] = p1 + cb[1];
        }
    }
}

// ---------------- launch ----------------

extern "C" void kernel_launch(void* const* d_in, const int* in_sizes, int n_in,
                              void* d_out, int out_size, void* d_ws, size_t ws_size,
                              hipStream_t stream) {
    const float* x     = (const float*)d_in[0];
    const int*   ei    = (const int*)d_in[1];
    const float* in_w  = (const float*)d_in[2];
    const float* in_b  = (const float*)d_in[3];
    const float* cls_w = (const float*)d_in[4];
    const float* cls_b = (const float*)d_in[5];
    const float* blk_w[3][5]; // lw, lb, rw, g, bt
    for (int bidx = 0; bidx < 3; ++bidx)
        for (int k = 0; k < 5; ++k)
            blk_w[bidx][k] = (const float*)d_in[6 + bidx * 5 + k];

    const int* src = ei;
    const int* dst = ei + NE;

    // workspace layout (~59 MB). binbuf (8.4 MB) overlays tmp (CSR phase only).
    size_t off = 0;
    auto alloc = [&](size_t bytes) {
        void* p = (char*)d_ws + off;
        off += (bytes + 255) & ~(size_t)255;
        return p;
    };
    u16*   h      = (u16*)alloc((size_t)NN * HD * 2);   // 25.6 MB
    u16*   tmp    = (u16*)alloc((size_t)NN * HD * 2);   // 25.6 MB (binbuf, then mean/pre-BN out)
    int*   rp     = (int*)alloc((size_t)(NN + 1) * 4);
    int*   cnt    = (int*)alloc((size_t)NN * 4);        // written non-atomically, no memset
    int*   col    = (int*)alloc((size_t)NE * 4);        // 6.4 MB
    int*   stot   = (int*)alloc((size_t)SCAN_BLOCKS * 4);
    u16*   wtb    = (u16*)alloc((size_t)7 * HD * HD * 2); // 224 KB transposed bf16 weights
    const size_t off_z = off;
    float* stats  = (float*)alloc((size_t)3 * 256 * 4);
    int*   binCur = (int*)alloc((size_t)NRANGE * 4);
    const size_t zspan = off - off_z;                   // stats+binCur, one memset
    u32*   binbuf = (u32*)tmp;                          // 128 bins x 16384 u32 = 8.4 MB
    (void)ws_size; (void)n_in; (void)in_sizes; (void)out_size;

    (void)hipMemsetAsync(stats, 0, zspan, stream);

    // transposed bf16 weights: [0]=in_w, then per block lw, rw
    WTArgs wa;
    wa.w[0] = in_w;
    for (int bidx = 0; bidx < 3; ++bidx) {
        wa.w[1 + bidx * 2] = blk_w[bidx][0]; // lw
        wa.w[2 + bidx * 2] = blk_w[bidx][2]; // rw
    }
    for (int m = 0; m < 7; ++m) wa.o[m] = wtb + (size_t)m * HD * HD;
    k_wt<<<dim3(HD, 7), HD, 0, stream>>>(wa);

    // CSR build: partition once, LDS-local count + fill (no per-edge global atomics)
    k_part<<<PART_GRID, 256, 0, stream>>>(src, dst, binCur, binbuf);
    k_countL<<<NRANGE, 1024, 0, stream>>>(binCur, binbuf, cnt);
    k_scan1<<<SCAN_BLOCKS, 256, 0, stream>>>(cnt, rp, stot);
    k_scan2<<<1, 128, 0, stream>>>(stot, rp);
    k_scan3<<<(NN + 255) / 256, 256, 0, stream>>>(rp, stot);
    k_fillL<<<NRANGE, 1024, 0, stream>>>(binCur, binbuf, rp, col);

    const int gemm_grid  = (NN + 127) / 128; // 782 blocks
    const int apply_grid = NN * 32 / 256;    // 12500, exact

    // input layer: h = relu(x @ in_w + in_b)
    k_mgemm<1, 1, 0><<<gemm_grid, 256, 0, stream>>>(x, wtb, nullptr, nullptr, in_b, h, nullptr);

    for (int bidx = 0; bidx < 3; ++bidx) {
        const u16* lwT = wtb + (size_t)(1 + bidx * 2) * HD * HD;
        const u16* rwT = wtb + (size_t)(2 + bidx * 2) * HD * HD;
        const float* lb = blk_w[bidx][1];
        const float* g  = blk_w[bidx][3];
        const float* bt = blk_w[bidx][4];
        float* st = stats + bidx * 256;
        k_agg<<<NN / 4, 256, 0, stream>>>(h, rp, col, tmp);
        k_mgemm<0, 0, 1><<<gemm_grid, 256, 0, stream>>>(tmp, lwT, h, rwT, lb, tmp, st);
        if (bidx < 2)
            k_apply<0><<<apply_grid, 256, 0, stream>>>(tmp, st, g, bt, h,
                                                       nullptr, nullptr, nullptr);
        else
            k_apply<1><<<apply_grid, 256, 0, stream>>>(tmp, st, g, bt, h,
                                                       cls_w, cls_b, (float*)d_out);
    }
}